// Round 5
// baseline (400.260 us; speedup 1.0000x reference)
//
#include <hip/hip_runtime.h>
#include <hip/hip_bf16.h>
#include <math.h>

#define B_ 4
#define P_ 2048
#define D_ 768
#define H_ 12

typedef __attribute__((ext_vector_type(8))) short bf16x8;
typedef __attribute__((ext_vector_type(4))) float f32x4;

static __device__ __forceinline__ short f2bf(float f) {
  union { float f; unsigned u; } z; z.f = f;
  unsigned r = z.u + 0x7fffu + ((z.u >> 16) & 1u);
  return (short)(r >> 16);
}

static __device__ __forceinline__ float bf2f(short s) {
  union { unsigned u; float f; } z;
  z.u = ((unsigned)(unsigned short)s) << 16;
  return z.f;
}

static __device__ __forceinline__ void gll16(const void* g, void* l) {
  __builtin_amdgcn_global_load_lds(
      (const __attribute__((address_space(1))) void*)g,
      (__attribute__((address_space(3))) void*)l, 16, 0, 0);
}

// V-LDS column swizzle: makes both transposed b16 writes and b128 reads bank-ideal.
static __device__ __forceinline__ int vswz(int d) {
  return ((d & 7) ^ ((d >> 3) & 7)) << 3;
}

// Tiled transpose + fp32->bf16: out[N][K] = cvt(in[K][N])
__global__ __launch_bounds__(256) void tcvt_kernel(const float* __restrict__ in,
                                                   short* __restrict__ out, int K, int N) {
  __shared__ float t[32][33];
  int k0 = blockIdx.x * 32, n0 = blockIdx.y * 32;
  int tx = threadIdx.x & 31, ty = threadIdx.x >> 5;
#pragma unroll
  for (int i = 0; i < 4; ++i)
    t[ty + 8 * i][tx] = in[(size_t)(k0 + ty + 8 * i) * N + n0 + tx];
  __syncthreads();
#pragma unroll
  for (int i = 0; i < 4; ++i)
    out[(size_t)(n0 + ty + 8 * i) * K + k0 + tx] = f2bf(t[tx][ty + 8 * i]);
}

// One block per row of 768. Reads f32, writes bf16 normalized row.
__global__ __launch_bounds__(256) void ln_kernel(const float* __restrict__ in,
                                                 const float* __restrict__ g,
                                                 const float* __restrict__ be,
                                                 short* __restrict__ out) {
  int row = blockIdx.x, tid = threadIdx.x;
  const float* xr = in + (size_t)row * D_;
  float v0 = xr[tid], v1 = xr[tid + 256], v2 = xr[tid + 512];
  float s = v0 + v1 + v2;
  float ss = v0 * v0 + v1 * v1 + v2 * v2;
#pragma unroll
  for (int d = 1; d < 64; d <<= 1) {
    s += __shfl_xor(s, d, 64);
    ss += __shfl_xor(ss, d, 64);
  }
  __shared__ float red[8];
  int w = tid >> 6;
  if ((tid & 63) == 0) { red[w] = s; red[4 + w] = ss; }
  __syncthreads();
  s = red[0] + red[1] + red[2] + red[3];
  ss = red[4] + red[5] + red[6] + red[7];
  float mu = s * (1.0f / D_);
  float rstd = rsqrtf(ss * (1.0f / D_) - mu * mu + 1e-3f);
  short* orow = out + (size_t)row * D_;
  orow[tid]       = f2bf((v0 - mu) * rstd * g[tid]       + be[tid]);
  orow[tid + 256] = f2bf((v1 - mu) * rstd * g[tid + 256] + be[tid + 256]);
  orow[tid + 512] = f2bf((v2 - mu) * rstd * g[tid + 512] + be[tid + 512]);
}

// C[M,N] = A[M,K](bf16) @ Bt[N,K]^T(bf16) + bias. 128x128 tile, BK=32,
// double-buffered LDS, single barrier per K-step (T3 minimum-2-phase recipe):
// stage(t+1) issued BEFORE ds_read+MFMA(t); __syncthreads' implicit
// vmcnt(0)+lgkmcnt(0) drain is the buffer handoff.
// EPI=0: ->bf16  EPI=1: gelu->bf16  EPI=2: *0.9+resid ->f32
template <int EPI>
__global__ __launch_bounds__(256, 3) void gemm128(
    const short* __restrict__ A, const short* __restrict__ Bt,
    const float* __restrict__ bias, short* __restrict__ out_bf,
    float* __restrict__ out_f, const float* __restrict__ resid,
    int M, int N, int K) {
  alignas(16) __shared__ short a_lds[2][128 * 32];
  alignas(16) __shared__ short b_lds[2][128 * 32];
  const int tid = threadIdx.x;
  const int wv = tid >> 6, lane = tid & 63;
  const int wm = wv >> 1, wn = wv & 1;
  const int g = lane >> 4, r = lane & 15;
  const int m0 = blockIdx.x * 128, n0 = blockIdx.y * 128;
  const int srow = lane >> 2, sseg = lane & 3;
  f32x4 acc[4][4] = {};
  const short* aptr = A + (size_t)(m0 + wv * 16 + srow) * K + sseg * 8;
  const short* bptr = Bt + (size_t)(n0 + wv * 16 + srow) * K + sseg * 8;
  const int aoff = (wv * 16) * 32;

  // prologue: stage K-tile 0 into buf 0
  gll16(aptr, &a_lds[0][aoff]);
  gll16(aptr + (size_t)64 * K, &a_lds[0][aoff + 64 * 32]);
  gll16(bptr, &b_lds[0][aoff]);
  gll16(bptr + (size_t)64 * K, &b_lds[0][aoff + 64 * 32]);
  __syncthreads();

  const int nt = K / 32;
  int cur = 0;
  for (int t = 0; t < nt; ++t) {
    if (t + 1 < nt) {
      const int k0 = (t + 1) * 32;
      const int nb = cur ^ 1;
      gll16(aptr + k0, &a_lds[nb][aoff]);
      gll16(aptr + k0 + (size_t)64 * K, &a_lds[nb][aoff + 64 * 32]);
      gll16(bptr + k0, &b_lds[nb][aoff]);
      gll16(bptr + k0 + (size_t)64 * K, &b_lds[nb][aoff + 64 * 32]);
    }
    bf16x8 af[4], bfr[4];
#pragma unroll
    for (int i = 0; i < 4; ++i)
      af[i] = *reinterpret_cast<const bf16x8*>(&a_lds[cur][(wm * 64 + i * 16 + r) * 32 + g * 8]);
#pragma unroll
    for (int i = 0; i < 4; ++i)
      bfr[i] = *reinterpret_cast<const bf16x8*>(&b_lds[cur][(wn * 64 + i * 16 + r) * 32 + g * 8]);
#pragma unroll
    for (int i = 0; i < 4; ++i)
#pragma unroll
      for (int jn = 0; jn < 4; ++jn)
        acc[i][jn] = __builtin_amdgcn_mfma_f32_16x16x32_bf16(af[i], bfr[jn], acc[i][jn], 0, 0, 0);
    __syncthreads();  // drains vmcnt(0)+lgkmcnt(0): staged tile ready, reads done
    cur ^= 1;
  }
#pragma unroll
  for (int i = 0; i < 4; ++i) {
#pragma unroll
    for (int jn = 0; jn < 4; ++jn) {
      int col = n0 + wn * 64 + jn * 16 + r;
      float bb = bias[col];
#pragma unroll
      for (int jj = 0; jj < 4; ++jj) {
        int row = m0 + wm * 64 + i * 16 + g * 4 + jj;
        float v = acc[i][jn][jj] + bb;
        size_t idx = (size_t)row * N + col;
        if (EPI == 0) {
          out_bf[idx] = f2bf(v);
        } else if (EPI == 1) {
          v = 0.5f * v * (1.0f + erff(v * 0.70710678118654752f));
          out_bf[idx] = f2bf(v);
        } else {
          out_f[idx] = v * 0.9f + resid[idx];
        }
      }
    }
  }
}

// Flash attention: grid (P/128, B*H). 4 waves, each owns 32 q rows (2 m-frags).
// Swapped QK^T (S^T = mfma(K,Q)): lane-local softmax. Defer-max (T13, THR=8):
// skip rescale when per-tile max growth <= 8.
__global__ __launch_bounds__(256, 3) void attn_kernel(const short* __restrict__ qkv,
                                                      const float* __restrict__ x,
                                                      float* __restrict__ x2) {
  alignas(16) __shared__ short k_lds[64 * 72];
  alignas(16) __shared__ short vt_lds[64 * 64];
  alignas(16) __shared__ short p_lds[4][32 * 72];
  const int tid = threadIdx.x, wv = tid >> 6, lane = tid & 63;
  const int g = lane >> 4, r = lane & 15;
  const int b = blockIdx.y / H_, h = blockIdx.y % H_;
  const int TD = 3 * D_;
  const int qrow0 = blockIdx.x * 128 + wv * 32;
  // Q fragments with 1/sqrt(hd)=0.125 folded in (exact: power-of-2 scale in bf16)
  bf16x8 qf[2][2];
#pragma unroll
  for (int mf = 0; mf < 2; ++mf)
#pragma unroll
    for (int kb = 0; kb < 2; ++kb) {
      bf16x8 q = *reinterpret_cast<const bf16x8*>(
          qkv + (size_t)(b * P_ + qrow0 + mf * 16 + r) * TD + h * 64 + kb * 32 + g * 8);
#pragma unroll
      for (int e = 0; e < 8; ++e) q[e] = f2bf(bf2f(q[e]) * 0.125f);
      qf[mf][kb] = q;
    }
  f32x4 acc[2][4] = {};
  float m_run[2], l_run[2];
#pragma unroll
  for (int mf = 0; mf < 2; ++mf) { m_run[mf] = -1e30f; l_run[mf] = 0.0f; }
  const int lrow = tid >> 2, lseg = tid & 3;
  short* p_w = &p_lds[wv][0];
  const int bcast = 20 * g;  // src lane 16*g + (4*g + j): holds q-row r=4g+j
  for (int kc = 0; kc < P_; kc += 64) {
    // prefetch K/V rows to registers before the barrier (overlap with prev compute)
    const short* src = qkv + (size_t)(b * P_ + kc + lrow) * TD + D_ + h * 64 + lseg * 16;
    bf16x8 kv0 = *reinterpret_cast<const bf16x8*>(src);
    bf16x8 kv1 = *reinterpret_cast<const bf16x8*>(src + 8);
    bf16x8 vv0 = *reinterpret_cast<const bf16x8*>(src + D_);
    bf16x8 vv1 = *reinterpret_cast<const bf16x8*>(src + D_ + 8);
    __syncthreads();
    *reinterpret_cast<bf16x8*>(&k_lds[lrow * 72 + lseg * 16]) = kv0;
    *reinterpret_cast<bf16x8*>(&k_lds[lrow * 72 + lseg * 16 + 8]) = kv1;
#pragma unroll
    for (int j = 0; j < 8; ++j) {
      int d0 = lseg * 16 + j, d1 = d0 + 8;
      vt_lds[d0 * 64 + (lrow ^ vswz(d0))] = vv0[j];
      vt_lds[d1 * 64 + (lrow ^ vswz(d1))] = vv1[j];
    }
    __syncthreads();
    // swapped QK^T -> S^T: lane holds S[q = mf*16+r][k = cf*16 + 4g + j]
    f32x4 st[2][4];
#pragma unroll
    for (int cf = 0; cf < 4; ++cf) {
      bf16x8 kf0 = *reinterpret_cast<const bf16x8*>(&k_lds[(cf * 16 + r) * 72 + g * 8]);
      bf16x8 kf1 = *reinterpret_cast<const bf16x8*>(&k_lds[(cf * 16 + r) * 72 + 32 + g * 8]);
#pragma unroll
      for (int mf = 0; mf < 2; ++mf) {
        f32x4 s = {};
        s = __builtin_amdgcn_mfma_f32_16x16x32_bf16(kf0, qf[mf][0], s, 0, 0, 0);
        s = __builtin_amdgcn_mfma_f32_16x16x32_bf16(kf1, qf[mf][1], s, 0, 0, 0);
        st[mf][cf] = s;
      }
    }
    // lane-local online softmax with defer-max
#pragma unroll
    for (int mf = 0; mf < 2; ++mf) {
      float mx = st[mf][0][0];
#pragma unroll
      for (int cf = 0; cf < 4; ++cf)
#pragma unroll
        for (int j = 0; j < 4; ++j) mx = fmaxf(mx, st[mf][cf][j]);
      mx = fmaxf(mx, __shfl_xor(mx, 16, 64));
      mx = fmaxf(mx, __shfl_xor(mx, 32, 64));
      if (!__all(mx - m_run[mf] <= 8.0f)) {
        float mn = fmaxf(m_run[mf], mx);
        float corr = __expf(m_run[mf] - mn);   // first tile: exp(-inf)=0
        m_run[mf] = mn;
        l_run[mf] *= corr;
        float cb0 = __shfl(corr, bcast + 0, 64);
        float cb1 = __shfl(corr, bcast + 1, 64);
        float cb2 = __shfl(corr, bcast + 2, 64);
        float cb3 = __shfl(corr, bcast + 3, 64);
#pragma unroll
        for (int cf = 0; cf < 4; ++cf) {
          acc[mf][cf][0] *= cb0; acc[mf][cf][1] *= cb1;
          acc[mf][cf][2] *= cb2; acc[mf][cf][3] *= cb3;
        }
      }
      float mn = m_run[mf];
      float p[4][4];
      float ls = 0.0f;
#pragma unroll
      for (int cf = 0; cf < 4; ++cf)
#pragma unroll
        for (int j = 0; j < 4; ++j) {
          float pv = __expf(st[mf][cf][j] - mn);
          p[cf][j] = pv;
          ls += pv;
        }
      ls += __shfl_xor(ls, 16, 64);
      ls += __shfl_xor(ls, 32, 64);
      l_run[mf] += ls;
      // write P^T row (q = mf*16 + r), packed pairs, b64 per cf
      short* prow = &p_w[(mf * 16 + r) * 72];
#pragma unroll
      for (int cf = 0; cf < 4; ++cf) {
        __hip_bfloat162 lo = __float22bfloat162_rn(make_float2(p[cf][0], p[cf][1]));
        __hip_bfloat162 hi = __float22bfloat162_rn(make_float2(p[cf][2], p[cf][3]));
        union { __hip_bfloat162 h2; unsigned u; } c0, c1;
        c0.h2 = lo; c1.h2 = hi;
        *reinterpret_cast<uint2*>(&prow[cf * 16 + 4 * g]) = make_uint2(c0.u, c1.u);
      }
    }
    // PV: vector V fragments from swizzled vt_lds
    bf16x8 vf[4][2];
#pragma unroll
    for (int cf = 0; cf < 4; ++cf) {
      int d = cf * 16 + r;
      int sw = vswz(d);
      vf[cf][0] = *reinterpret_cast<const bf16x8*>(&vt_lds[d * 64 + ((g * 8) ^ sw)]);
      vf[cf][1] = *reinterpret_cast<const bf16x8*>(&vt_lds[d * 64 + ((32 + g * 8) ^ sw)]);
    }
#pragma unroll
    for (int mf = 0; mf < 2; ++mf) {
      bf16x8 pf0 = *reinterpret_cast<const bf16x8*>(&p_w[(mf * 16 + r) * 72 + g * 8]);
      bf16x8 pf1 = *reinterpret_cast<const bf16x8*>(&p_w[(mf * 16 + r) * 72 + 32 + g * 8]);
#pragma unroll
      for (int cf = 0; cf < 4; ++cf) {
        acc[mf][cf] = __builtin_amdgcn_mfma_f32_16x16x32_bf16(pf0, vf[cf][0], acc[mf][cf], 0, 0, 0);
        acc[mf][cf] = __builtin_amdgcn_mfma_f32_16x16x32_bf16(pf1, vf[cf][1], acc[mf][cf], 0, 0, 0);
      }
    }
  }
#pragma unroll
  for (int mf = 0; mf < 2; ++mf) {
    float lb0 = 0.9f / __shfl(l_run[mf], bcast + 0, 64);
    float lb1 = 0.9f / __shfl(l_run[mf], bcast + 1, 64);
    float lb2 = 0.9f / __shfl(l_run[mf], bcast + 2, 64);
    float lb3 = 0.9f / __shfl(l_run[mf], bcast + 3, 64);
    float lb[4] = {lb0, lb1, lb2, lb3};
#pragma unroll
    for (int cf = 0; cf < 4; ++cf) {
      int col = h * 64 + cf * 16 + r;
#pragma unroll
      for (int j = 0; j < 4; ++j) {
        int row = qrow0 + mf * 16 + g * 4 + j;
        size_t idx = (size_t)(b * P_ + row) * D_ + col;
        x2[idx] = acc[mf][cf][j] * lb[j] + x[idx];
      }
    }
  }
}

extern "C" void kernel_launch(void* const* d_in, const int* in_sizes, int n_in,
                              void* d_out, int out_size, void* d_ws, size_t ws_size,
                              hipStream_t stream) {
  const float* x     = (const float*)d_in[0];
  const float* ln1_g = (const float*)d_in[1];
  const float* ln1_b = (const float*)d_in[2];
  const float* w_qkv = (const float*)d_in[3];
  const float* b_qkv = (const float*)d_in[4];
  const float* ln2_g = (const float*)d_in[5];
  const float* ln2_b = (const float*)d_in[6];
  const float* w1    = (const float*)d_in[7];
  const float* b1    = (const float*)d_in[8];
  const float* w2    = (const float*)d_in[9];
  const float* b2    = (const float*)d_in[10];
  float* out = (float*)d_out;
  char* ws = (char*)d_ws;

  short* wqkv_t = (short*)(ws);                 // [2304][768]  = 3,538,944 B
  short* w1_t   = (short*)(ws + 3538944);       // [3072][768]  = 4,718,592 B
  short* w2_t   = (short*)(ws + 8257536);       // [768][3072]  = 4,718,592 B
  short* h_bf   = (short*)(ws + 12976128);      // [8192][768]  = 12,582,912 B
  short* qkv_bf = (short*)(ws + 25559040);      // [8192][2304] = 37,748,736 B
  short* a1_bf  = qkv_bf;                       // reused: [8192][3072] = 50,331,648 B

  const int R = B_ * P_;  // 8192 rows

  { dim3 g2(768 / 32, 2304 / 32);  tcvt_kernel<<<g2, 256, 0, stream>>>(w_qkv, wqkv_t, 768, 2304); }
  { dim3 g2(768 / 32, 3072 / 32);  tcvt_kernel<<<g2, 256, 0, stream>>>(w1, w1_t, 768, 3072); }
  { dim3 g2(3072 / 32, 768 / 32);  tcvt_kernel<<<g2, 256, 0, stream>>>(w2, w2_t, 3072, 768); }

  ln_kernel<<<R, 256, 0, stream>>>(x, ln1_g, ln1_b, h_bf);

  {
    dim3 grid(R / 128, 2304 / 128);
    gemm128<0><<<grid, 256, 0, stream>>>(h_bf, wqkv_t, b_qkv, qkv_bf, nullptr, nullptr,
                                         R, 2304, 768);
  }
  {
    dim3 grid(P_ / 128, B_ * H_);
    attn_kernel<<<grid, 256, 0, stream>>>(qkv_bf, x, out);
  }
  ln_kernel<<<R, 256, 0, stream>>>(out, ln2_g, ln2_b, h_bf);
  {
    dim3 grid(R / 128, 3072 / 128);
    gemm128<1><<<grid, 256, 0, stream>>>(h_bf, w1_t, b1, a1_bf, nullptr, nullptr,
                                         R, 3072, 768);
  }
  {
    dim3 grid(R / 128, 768 / 128);
    gemm128<2><<<grid, 256, 0, stream>>>(a1_bf, w2_t, b2, nullptr, out, out,
                                         R, 768, 3072);
  }
}

// Round 7
// 394.844 us; speedup vs baseline: 1.0137x; 1.0137x over previous
//
#include <hip/hip_runtime.h>
#include <hip/hip_bf16.h>
#include <math.h>

#define B_ 4
#define P_ 2048
#define D_ 768
#define H_ 12

typedef __attribute__((ext_vector_type(8))) short bf16x8;
typedef __attribute__((ext_vector_type(4))) float f32x4;

static __device__ __forceinline__ short f2bf(float f) {
  union { float f; unsigned u; } z; z.f = f;
  unsigned r = z.u + 0x7fffu + ((z.u >> 16) & 1u);
  return (short)(r >> 16);
}

static __device__ __forceinline__ float bf2f(short s) {
  union { unsigned u; float f; } z;
  z.u = ((unsigned)(unsigned short)s) << 16;
  return z.f;
}

static __device__ __forceinline__ void gll16(const void* g, void* l) {
  __builtin_amdgcn_global_load_lds(
      (const __attribute__((address_space(1))) void*)g,
      (__attribute__((address_space(3))) void*)l, 16, 0, 0);
}

// Tiled transpose + fp32->bf16: out[N][K] = cvt(in[K][N])
__global__ __launch_bounds__(256) void tcvt_kernel(const float* __restrict__ in,
                                                   short* __restrict__ out, int K, int N) {
  __shared__ float t[32][33];
  int k0 = blockIdx.x * 32, n0 = blockIdx.y * 32;
  int tx = threadIdx.x & 31, ty = threadIdx.x >> 5;
#pragma unroll
  for (int i = 0; i < 4; ++i)
    t[ty + 8 * i][tx] = in[(size_t)(k0 + ty + 8 * i) * N + n0 + tx];
  __syncthreads();
#pragma unroll
  for (int i = 0; i < 4; ++i)
    out[(size_t)(n0 + ty + 8 * i) * K + k0 + tx] = f2bf(t[tx][ty + 8 * i]);
}

// One block per row of 768. Reads f32, writes bf16 normalized row.
__global__ __launch_bounds__(256) void ln_kernel(const float* __restrict__ in,
                                                 const float* __restrict__ g,
                                                 const float* __restrict__ be,
                                                 short* __restrict__ out) {
  int row = blockIdx.x, tid = threadIdx.x;
  const float* xr = in + (size_t)row * D_;
  float v0 = xr[tid], v1 = xr[tid + 256], v2 = xr[tid + 512];
  float s = v0 + v1 + v2;
  float ss = v0 * v0 + v1 * v1 + v2 * v2;
#pragma unroll
  for (int d = 1; d < 64; d <<= 1) {
    s += __shfl_xor(s, d, 64);
    ss += __shfl_xor(ss, d, 64);
  }
  __shared__ float red[8];
  int w = tid >> 6;
  if ((tid & 63) == 0) { red[w] = s; red[4 + w] = ss; }
  __syncthreads();
  s = red[0] + red[1] + red[2] + red[3];
  ss = red[4] + red[5] + red[6] + red[7];
  float mu = s * (1.0f / D_);
  float rstd = rsqrtf(ss * (1.0f / D_) - mu * mu + 1e-3f);
  short* orow = out + (size_t)row * D_;
  orow[tid]       = f2bf((v0 - mu) * rstd * g[tid]       + be[tid]);
  orow[tid + 256] = f2bf((v1 - mu) * rstd * g[tid + 256] + be[tid + 256]);
  orow[tid + 512] = f2bf((v2 - mu) * rstd * g[tid + 512] + be[tid + 512]);
}

// C[M,N] = A[M,K](bf16) @ Bt[N,K]^T(bf16) + bias. 128x128, BK=32, dbuf.
// LDS XOR-swizzle (T2 probe): source col ^= (row&3), read col ^= (row&3).
// EPI=0: ->bf16  EPI=1: gelu->bf16  EPI=2: *0.9+resid ->f32
template <int EPI>
__global__ __launch_bounds__(256, 3) void gemm128(
    const short* __restrict__ A, const short* __restrict__ Bt,
    const float* __restrict__ bias, short* __restrict__ out_bf,
    float* __restrict__ out_f, const float* __restrict__ resid,
    int M, int N, int K) {
  alignas(16) __shared__ short a_lds[2][128 * 32];
  alignas(16) __shared__ short b_lds[2][128 * 32];
  const int tid = threadIdx.x;
  const int wv = tid >> 6, lane = tid & 63;
  const int wm = wv >> 1, wn = wv & 1;
  const int g = lane >> 4, r = lane & 15;
  const int m0 = blockIdx.x * 128, n0 = blockIdx.y * 128;
  const int srow = lane >> 2, sseg = lane & 3;
  f32x4 acc[4][4] = {};
  // inverse-swizzled global source (rule 21): data for dest col c comes from col c^(row&3)
  const int sw_seg = sseg ^ (srow & 3);
  const short* aptr = A + (size_t)(m0 + wv * 16 + srow) * K + sw_seg * 8;
  const short* bptr = Bt + (size_t)(n0 + wv * 16 + srow) * K + sw_seg * 8;
  const int aoff = (wv * 16) * 32;

  gll16(aptr, &a_lds[0][aoff]);
  gll16(aptr + (size_t)64 * K, &a_lds[0][aoff + 64 * 32]);
  gll16(bptr, &b_lds[0][aoff]);
  gll16(bptr + (size_t)64 * K, &b_lds[0][aoff + 64 * 32]);
  __syncthreads();

  const int nt = K / 32;
  int cur = 0;
  for (int t = 0; t < nt; ++t) {
    if (t + 1 < nt) {
      const int k0 = (t + 1) * 32;
      const int nb = cur ^ 1;
      gll16(aptr + k0, &a_lds[nb][aoff]);
      gll16(aptr + k0 + (size_t)64 * K, &a_lds[nb][aoff + 64 * 32]);
      gll16(bptr + k0, &b_lds[nb][aoff]);
      gll16(bptr + k0 + (size_t)64 * K, &b_lds[nb][aoff + 64 * 32]);
    }
    bf16x8 af[4], bfr[4];
#pragma unroll
    for (int i = 0; i < 4; ++i)
      af[i] = *reinterpret_cast<const bf16x8*>(
          &a_lds[cur][(wm * 64 + i * 16 + r) * 32 + ((g ^ (r & 3)) * 8)]);
#pragma unroll
    for (int i = 0; i < 4; ++i)
      bfr[i] = *reinterpret_cast<const bf16x8*>(
          &b_lds[cur][(wn * 64 + i * 16 + r) * 32 + ((g ^ (r & 3)) * 8)]);
#pragma unroll
    for (int i = 0; i < 4; ++i)
#pragma unroll
      for (int jn = 0; jn < 4; ++jn)
        acc[i][jn] = __builtin_amdgcn_mfma_f32_16x16x32_bf16(af[i], bfr[jn], acc[i][jn], 0, 0, 0);
    __syncthreads();
    cur ^= 1;
  }
#pragma unroll
  for (int i = 0; i < 4; ++i) {
#pragma unroll
    for (int jn = 0; jn < 4; ++jn) {
      int col = n0 + wn * 64 + jn * 16 + r;
      float bb = bias[col];
#pragma unroll
      for (int jj = 0; jj < 4; ++jj) {
        int row = m0 + wm * 64 + i * 16 + g * 4 + jj;
        float v = acc[i][jn][jj] + bb;
        size_t idx = (size_t)row * N + col;
        if (EPI == 0) {
          out_bf[idx] = f2bf(v);
        } else if (EPI == 1) {
          v = 0.5f * v * (1.0f + erff(v * 0.70710678118654752f));
          out_bf[idx] = f2bf(v);
        } else {
          out_f[idx] = v * 0.9f + resid[idx];
        }
      }
    }
  }
}

// Flash attention: grid (P/128, B*H). 4 waves x 32 q-rows. KVBLK=128.
// All LDS XOR-swizzled (byte ^= (row&7)<<4) -> b128 reads at bank floor.
// T14: K/V loads for tile t+1 issued right after QK^T, consumed next iter.
__global__ __launch_bounds__(256, 2) void attn_kernel(const short* __restrict__ qkv,
                                                      const float* __restrict__ x,
                                                      float* __restrict__ x2) {
  alignas(16) __shared__ short k_lds[128 * 64];   // [krow][d]   16 KB
  alignas(16) __shared__ short vt_lds[64 * 128];  // [d][krow]   16 KB
  alignas(16) __shared__ short p_lds[4][32 * 128];// [q][k]/wave 32 KB
  const int tid = threadIdx.x, wv = tid >> 6, lane = tid & 63;
  const int g = lane >> 4, r = lane & 15;
  const int b = blockIdx.y / H_, h = blockIdx.y % H_;
  const int TD = 3 * D_;
  const int qrow0 = blockIdx.x * 128 + wv * 32;
  bf16x8 qf[2][2];
#pragma unroll
  for (int mf = 0; mf < 2; ++mf)
#pragma unroll
    for (int kb = 0; kb < 2; ++kb) {
      bf16x8 q = *reinterpret_cast<const bf16x8*>(
          qkv + (size_t)(b * P_ + qrow0 + mf * 16 + r) * TD + h * 64 + kb * 32 + g * 8);
#pragma unroll
      for (int e = 0; e < 8; ++e) q[e] = f2bf(bf2f(q[e]) * 0.125f);
      qf[mf][kb] = q;
    }
  f32x4 acc[2][4] = {};
  float m_run[2], l_run[2];
#pragma unroll
  for (int mf = 0; mf < 2; ++mf) { m_run[mf] = -1e30f; l_run[mf] = 0.0f; }

  const int krow = tid >> 1, dhalf = tid & 1;
  const short* kv0src = qkv + (size_t)(b * P_ + krow) * TD + D_ + h * 64 + dhalf * 32;
  char* p_w = (char*)&p_lds[wv][0];
  const int bcast = 20 * g;  // src lane 16*g + (4*g + j)
  const int rsw = (r & 7) << 4;

  // prologue: load tile 0 into regs
  bf16x8 kreg[4], vreg[4];
#pragma unroll
  for (int c = 0; c < 4; ++c) {
    kreg[c] = *reinterpret_cast<const bf16x8*>(kv0src + c * 8);
    vreg[c] = *reinterpret_cast<const bf16x8*>(kv0src + D_ + c * 8);
  }

  for (int kc = 0; kc < P_; kc += 128) {
    __syncthreads();  // prev tile's LDS reads done
    {
      char* kb_ = (char*)&k_lds[krow * 64];
      const int ksw = (krow & 7) << 4;
#pragma unroll
      for (int c = 0; c < 4; ++c)
        *reinterpret_cast<bf16x8*>(kb_ + ((dhalf * 64 + c * 16) ^ ksw)) = kreg[c];
#pragma unroll
      for (int c = 0; c < 4; ++c)
#pragma unroll
        for (int j = 0; j < 8; ++j) {
          int d = dhalf * 32 + c * 8 + j;
          *reinterpret_cast<short*>((char*)vt_lds + d * 256 + ((krow * 2) ^ ((d & 7) << 4))) =
              vreg[c][j];
        }
    }
    __syncthreads();
    // swapped QK^T -> S^T: lane holds S[q = mf*16+r][k = cf*16 + 4g + j]
    f32x4 st[2][8];
#pragma unroll
    for (int cf = 0; cf < 8; ++cf) {
      int row = cf * 16 + r;
      const char* kb_ = (const char*)k_lds + row * 128;
      bf16x8 kf0 = *reinterpret_cast<const bf16x8*>(kb_ + ((g * 16) ^ rsw));
      bf16x8 kf1 = *reinterpret_cast<const bf16x8*>(kb_ + ((64 + g * 16) ^ rsw));
#pragma unroll
      for (int mf = 0; mf < 2; ++mf) {
        f32x4 s = {};
        s = __builtin_amdgcn_mfma_f32_16x16x32_bf16(kf0, qf[mf][0], s, 0, 0, 0);
        s = __builtin_amdgcn_mfma_f32_16x16x32_bf16(kf1, qf[mf][1], s, 0, 0, 0);
        st[mf][cf] = s;
      }
    }
    // T14: issue next tile's loads now; softmax+PV (~1000cy) covers the latency
    if (kc + 128 < P_) {
      const short* src = kv0src + (size_t)(kc + 128) * TD;
#pragma unroll
      for (int c = 0; c < 4; ++c) {
        kreg[c] = *reinterpret_cast<const bf16x8*>(src + c * 8);
        vreg[c] = *reinterpret_cast<const bf16x8*>(src + D_ + c * 8);
      }
    }
    // lane-local online softmax with defer-max
#pragma unroll
    for (int mf = 0; mf < 2; ++mf) {
      float mx = st[mf][0][0];
#pragma unroll
      for (int cf = 0; cf < 8; ++cf)
#pragma unroll
        for (int j = 0; j < 4; ++j) mx = fmaxf(mx, st[mf][cf][j]);
      mx = fmaxf(mx, __shfl_xor(mx, 16, 64));
      mx = fmaxf(mx, __shfl_xor(mx, 32, 64));
      if (!__all(mx - m_run[mf] <= 8.0f)) {
        float mn = fmaxf(m_run[mf], mx);
        float corr = __expf(m_run[mf] - mn);   // first tile: exp(-inf)=0
        m_run[mf] = mn;
        l_run[mf] *= corr;
        float cb0 = __shfl(corr, bcast + 0, 64);
        float cb1 = __shfl(corr, bcast + 1, 64);
        float cb2 = __shfl(corr, bcast + 2, 64);
        float cb3 = __shfl(corr, bcast + 3, 64);
#pragma unroll
        for (int cf = 0; cf < 4; ++cf) {
          acc[mf][cf][0] *= cb0; acc[mf][cf][1] *= cb1;
          acc[mf][cf][2] *= cb2; acc[mf][cf][3] *= cb3;
        }
      }
      float mn = m_run[mf];
      float ls = 0.0f;
      char* prow = p_w + (mf * 16 + r) * 256;
#pragma unroll
      for (int cf = 0; cf < 8; ++cf) {
        float p0 = __expf(st[mf][cf][0] - mn);
        float p1 = __expf(st[mf][cf][1] - mn);
        float p2 = __expf(st[mf][cf][2] - mn);
        float p3 = __expf(st[mf][cf][3] - mn);
        ls += (p0 + p1) + (p2 + p3);
        __hip_bfloat162 lo = __float22bfloat162_rn(make_float2(p0, p1));
        __hip_bfloat162 hi = __float22bfloat162_rn(make_float2(p2, p3));
        union { __hip_bfloat162 h2; unsigned u; } c0, c1;
        c0.h2 = lo; c1.h2 = hi;
        *reinterpret_cast<uint2*>(prow + ((cf * 32 + 8 * g) ^ rsw)) = make_uint2(c0.u, c1.u);
      }
      ls += __shfl_xor(ls, 16, 64);
      ls += __shfl_xor(ls, 32, 64);
      l_run[mf] += ls;
    }
    // PV: A = P^T rows (per-wave p_lds), B = V fragments from vt_lds
    bf16x8 vf[4][4];
#pragma unroll
    for (int cf = 0; cf < 4; ++cf) {
      int d = cf * 16 + r;
      const char* vb = (const char*)vt_lds + d * 256;
#pragma unroll
      for (int ks = 0; ks < 4; ++ks)
        vf[cf][ks] = *reinterpret_cast<const bf16x8*>(vb + ((ks * 64 + g * 16) ^ rsw));
    }
#pragma unroll
    for (int mf = 0; mf < 2; ++mf) {
      const char* prow = p_w + (mf * 16 + r) * 256;
#pragma unroll
      for (int ks = 0; ks < 4; ++ks) {
        bf16x8 pf = *reinterpret_cast<const bf16x8*>(prow + ((ks * 64 + g * 16) ^ rsw));
#pragma unroll
        for (int cf = 0; cf < 4; ++cf)
          acc[mf][cf] = __builtin_amdgcn_mfma_f32_16x16x32_bf16(pf, vf[cf][ks], acc[mf][cf], 0, 0, 0);
      }
    }
  }
#pragma unroll
  for (int mf = 0; mf < 2; ++mf) {
    float lb0 = 0.9f / __shfl(l_run[mf], bcast + 0, 64);
    float lb1 = 0.9f / __shfl(l_run[mf], bcast + 1, 64);
    float lb2 = 0.9f / __shfl(l_run[mf], bcast + 2, 64);
    float lb3 = 0.9f / __shfl(l_run[mf], bcast + 3, 64);
    float lb[4] = {lb0, lb1, lb2, lb3};
#pragma unroll
    for (int cf = 0; cf < 4; ++cf) {
      int col = h * 64 + cf * 16 + r;
#pragma unroll
      for (int j = 0; j < 4; ++j) {
        int row = qrow0 + mf * 16 + g * 4 + j;
        size_t idx = (size_t)(b * P_ + row) * D_ + col;
        x2[idx] = acc[mf][cf][j] * lb[j] + x[idx];
      }
    }
  }
}

extern "C" void kernel_launch(void* const* d_in, const int* in_sizes, int n_in,
                              void* d_out, int out_size, void* d_ws, size_t ws_size,
                              hipStream_t stream) {
  const float* x     = (const float*)d_in[0];
  const float* ln1_g = (const float*)d_in[1];
  const float* ln1_b = (const float*)d_in[2];
  const float* w_qkv = (const float*)d_in[3];
  const float* b_qkv = (const float*)d_in[4];
  const float* ln2_g = (const float*)d_in[5];
  const float* ln2_b = (const float*)d_in[6];
  const float* w1    = (const float*)d_in[7];
  const float* b1    = (const float*)d_in[8];
  const float* w2    = (const float*)d_in[9];
  const float* b2    = (const float*)d_in[10];
  float* out = (float*)d_out;
  char* ws = (char*)d_ws;

  short* wqkv_t = (short*)(ws);                 // [2304][768]
  short* w1_t   = (short*)(ws + 3538944);       // [3072][768]
  short* w2_t   = (short*)(ws + 8257536);       // [768][3072]
  short* h_bf   = (short*)(ws + 12976128);      // [8192][768]
  short* qkv_bf = (short*)(ws + 25559040);      // [8192][2304]
  short* a1_bf  = qkv_bf;                       // reused: [8192][3072]

  const int R = B_ * P_;  // 8192 rows

  { dim3 g2(768 / 32, 2304 / 32);  tcvt_kernel<<<g2, 256, 0, stream>>>(w_qkv, wqkv_t, 768, 2304); }
  { dim3 g2(768 / 32, 3072 / 32);  tcvt_kernel<<<g2, 256, 0, stream>>>(w1, w1_t, 768, 3072); }
  { dim3 g2(3072 / 32, 768 / 32);  tcvt_kernel<<<g2, 256, 0, stream>>>(w2, w2_t, 3072, 768); }

  ln_kernel<<<R, 256, 0, stream>>>(x, ln1_g, ln1_b, h_bf);

  {
    dim3 grid(R / 128, 2304 / 128);
    gemm128<0><<<grid, 256, 0, stream>>>(h_bf, wqkv_t, b_qkv, qkv_bf, nullptr, nullptr,
                                         R, 2304, 768);
  }
  {
    dim3 grid(P_ / 128, B_ * H_);
    attn_kernel<<<grid, 256, 0, stream>>>(qkv_bf, x, out);
  }
  ln_kernel<<<R, 256, 0, stream>>>(out, ln2_g, ln2_b, h_bf);
  {
    dim3 grid(R / 128, 3072 / 128);
    gemm128<1><<<grid, 256, 0, stream>>>(h_bf, w1_t, b1, a1_bf, nullptr, nullptr,
                                         R, 3072, 768);
  }
  {
    dim3 grid(R / 128, 768 / 128);
    gemm128<2><<<grid, 256, 0, stream>>>(a1_bf, w2_t, b2, nullptr, out, out,
                                         R, 768, 3072);
  }
}

// Round 8
// 388.471 us; speedup vs baseline: 1.0303x; 1.0164x over previous
//
#include <hip/hip_runtime.h>
#include <hip/hip_bf16.h>
#include <math.h>

#define B_ 4
#define P_ 2048
#define D_ 768
#define H_ 12

typedef __attribute__((ext_vector_type(8))) short bf16x8;
typedef __attribute__((ext_vector_type(4))) float f32x4;

static __device__ __forceinline__ short f2bf(float f) {
  union { float f; unsigned u; } z; z.f = f;
  unsigned r = z.u + 0x7fffu + ((z.u >> 16) & 1u);
  return (short)(r >> 16);
}

static __device__ __forceinline__ float bf2f(short s) {
  union { unsigned u; float f; } z;
  z.u = ((unsigned)(unsigned short)s) << 16;
  return z.f;
}

static __device__ __forceinline__ void gll16(const void* g, void* l) {
  __builtin_amdgcn_global_load_lds(
      (const __attribute__((address_space(1))) void*)g,
      (__attribute__((address_space(3))) void*)l, 16, 0, 0);
}

// V-LDS column swizzle: makes both transposed b16 writes and b128 reads bank-ideal.
static __device__ __forceinline__ int vswz(int d) {
  return ((d & 7) ^ ((d >> 3) & 7)) << 3;
}

// Tiled transpose + fp32->bf16: out[N][K] = cvt(in[K][N])
__global__ __launch_bounds__(256) void tcvt_kernel(const float* __restrict__ in,
                                                   short* __restrict__ out, int K, int N) {
  __shared__ float t[32][33];
  int k0 = blockIdx.x * 32, n0 = blockIdx.y * 32;
  int tx = threadIdx.x & 31, ty = threadIdx.x >> 5;
#pragma unroll
  for (int i = 0; i < 4; ++i)
    t[ty + 8 * i][tx] = in[(size_t)(k0 + ty + 8 * i) * N + n0 + tx];
  __syncthreads();
#pragma unroll
  for (int i = 0; i < 4; ++i)
    out[(size_t)(n0 + ty + 8 * i) * K + k0 + tx] = f2bf(t[tx][ty + 8 * i]);
}

// One block per row of 768. Reads f32, writes bf16 normalized row.
__global__ __launch_bounds__(256) void ln_kernel(const float* __restrict__ in,
                                                 const float* __restrict__ g,
                                                 const float* __restrict__ be,
                                                 short* __restrict__ out) {
  int row = blockIdx.x, tid = threadIdx.x;
  const float* xr = in + (size_t)row * D_;
  float v0 = xr[tid], v1 = xr[tid + 256], v2 = xr[tid + 512];
  float s = v0 + v1 + v2;
  float ss = v0 * v0 + v1 * v1 + v2 * v2;
#pragma unroll
  for (int d = 1; d < 64; d <<= 1) {
    s += __shfl_xor(s, d, 64);
    ss += __shfl_xor(ss, d, 64);
  }
  __shared__ float red[8];
  int w = tid >> 6;
  if ((tid & 63) == 0) { red[w] = s; red[4 + w] = ss; }
  __syncthreads();
  s = red[0] + red[1] + red[2] + red[3];
  ss = red[4] + red[5] + red[6] + red[7];
  float mu = s * (1.0f / D_);
  float rstd = rsqrtf(ss * (1.0f / D_) - mu * mu + 1e-3f);
  short* orow = out + (size_t)row * D_;
  orow[tid]       = f2bf((v0 - mu) * rstd * g[tid]       + be[tid]);
  orow[tid + 256] = f2bf((v1 - mu) * rstd * g[tid + 256] + be[tid + 256]);
  orow[tid + 512] = f2bf((v2 - mu) * rstd * g[tid + 512] + be[tid + 512]);
}

// C[M,N] = A[M,K](bf16) @ Bt[N,K]^T(bf16) + bias. 128x128, BK=32.
// T4 counted-vmcnt pipeline, 2 K-tiles deep: stage(t+2) issued mid-iter;
// bottom wait = vmcnt(4) (stage(t+1) landed, stage(t+2) still in flight).
// Raw s_barrier + manual waits; LDS XOR-swizzle on read path kept.
// EPI=0: ->bf16  EPI=1: gelu->bf16  EPI=2: *0.9+resid ->f32
template <int EPI>
__global__ __launch_bounds__(256, 3) void gemm128(
    const short* __restrict__ A, const short* __restrict__ Bt,
    const float* __restrict__ bias, short* __restrict__ out_bf,
    float* __restrict__ out_f, const float* __restrict__ resid,
    int M, int N, int K) {
  alignas(16) __shared__ short a_lds[2][128 * 32];
  alignas(16) __shared__ short b_lds[2][128 * 32];
  const int tid = threadIdx.x;
  const int wv = tid >> 6, lane = tid & 63;
  const int wm = wv >> 1, wn = wv & 1;
  const int g = lane >> 4, r = lane & 15;
  const int m0 = blockIdx.x * 128, n0 = blockIdx.y * 128;
  const int srow = lane >> 2, sseg = lane & 3;
  f32x4 acc[4][4] = {};
  // inverse-swizzled global source (rule 21): dest col c holds data of col c^(row&3)
  const int sw_seg = sseg ^ (srow & 3);
  const short* aptr = A + (size_t)(m0 + wv * 16 + srow) * K + sw_seg * 8;
  const short* bptr = Bt + (size_t)(n0 + wv * 16 + srow) * K + sw_seg * 8;
  const int aoff = (wv * 16) * 32;

  auto stage = [&](int k0, int buf) {
    gll16(aptr + k0, &a_lds[buf][aoff]);
    gll16(aptr + k0 + (size_t)64 * K, &a_lds[buf][aoff + 64 * 32]);
    gll16(bptr + k0, &b_lds[buf][aoff]);
    gll16(bptr + k0 + (size_t)64 * K, &b_lds[buf][aoff + 64 * 32]);
  };

  const int nt = K / 32;
  // prologue: 2 tiles in flight
  stage(0, 0);
  stage(32, 1);
  asm volatile("s_waitcnt vmcnt(4)" ::: "memory");  // tile 0 landed
  __builtin_amdgcn_s_barrier();
  __builtin_amdgcn_sched_barrier(0);

  for (int t = 0; t < nt; ++t) {
    const int cur = t & 1;
    bf16x8 af[4], bfr[4];
#pragma unroll
    for (int i = 0; i < 4; ++i)
      af[i] = *reinterpret_cast<const bf16x8*>(
          &a_lds[cur][(wm * 64 + i * 16 + r) * 32 + ((g ^ (r & 3)) * 8)]);
#pragma unroll
    for (int i = 0; i < 4; ++i)
      bfr[i] = *reinterpret_cast<const bf16x8*>(
          &b_lds[cur][(wn * 64 + i * 16 + r) * 32 + ((g ^ (r & 3)) * 8)]);
    asm volatile("s_waitcnt lgkmcnt(0)" ::: "memory");
    __builtin_amdgcn_sched_barrier(0);
    __builtin_amdgcn_s_barrier();          // all waves done reading buf[cur]
    __builtin_amdgcn_sched_barrier(0);
    if (t + 2 < nt) stage((t + 2) * 32, cur);  // overwrite-safe after barrier
#pragma unroll
    for (int i = 0; i < 4; ++i)
#pragma unroll
      for (int jn = 0; jn < 4; ++jn)
        acc[i][jn] = __builtin_amdgcn_mfma_f32_16x16x32_bf16(af[i], bfr[jn], acc[i][jn], 0, 0, 0);
    if (t + 1 < nt) {
      if (t + 2 < nt)
        asm volatile("s_waitcnt vmcnt(4)" ::: "memory");  // stage(t+1) landed
      else
        asm volatile("s_waitcnt vmcnt(0)" ::: "memory");  // last tile: drain
      __builtin_amdgcn_s_barrier();
      __builtin_amdgcn_sched_barrier(0);
    }
  }
#pragma unroll
  for (int i = 0; i < 4; ++i) {
#pragma unroll
    for (int jn = 0; jn < 4; ++jn) {
      int col = n0 + wn * 64 + jn * 16 + r;
      float bb = bias[col];
#pragma unroll
      for (int jj = 0; jj < 4; ++jj) {
        int row = m0 + wm * 64 + i * 16 + g * 4 + jj;
        float v = acc[i][jn][jj] + bb;
        size_t idx = (size_t)row * N + col;
        if (EPI == 0) {
          out_bf[idx] = f2bf(v);
        } else if (EPI == 1) {
          v = 0.5f * v * (1.0f + erff(v * 0.70710678118654752f));
          out_bf[idx] = f2bf(v);
        } else {
          out_f[idx] = v * 0.9f + resid[idx];
        }
      }
    }
  }
}

// Flash attention (revert to round-4-measured best: 114.8us).
// grid (P/128, B*H). 4 waves x 32 q rows. Swapped QK^T -> lane-local softmax.
__global__ __launch_bounds__(256, 3) void attn_kernel(const short* __restrict__ qkv,
                                                      const float* __restrict__ x,
                                                      float* __restrict__ x2) {
  alignas(16) __shared__ short k_lds[64 * 72];
  alignas(16) __shared__ short vt_lds[64 * 64];
  alignas(16) __shared__ short p_lds[4][32 * 72];
  const int tid = threadIdx.x, wv = tid >> 6, lane = tid & 63;
  const int g = lane >> 4, r = lane & 15;
  const int b = blockIdx.y / H_, h = blockIdx.y % H_;
  const int TD = 3 * D_;
  const int qrow0 = blockIdx.x * 128 + wv * 32;
  // Q fragments with 1/sqrt(hd)=0.125 folded in (exact: power-of-2 scale in bf16)
  bf16x8 qf[2][2];
#pragma unroll
  for (int mf = 0; mf < 2; ++mf)
#pragma unroll
    for (int kb = 0; kb < 2; ++kb) {
      bf16x8 q = *reinterpret_cast<const bf16x8*>(
          qkv + (size_t)(b * P_ + qrow0 + mf * 16 + r) * TD + h * 64 + kb * 32 + g * 8);
#pragma unroll
      for (int e = 0; e < 8; ++e) q[e] = f2bf(bf2f(q[e]) * 0.125f);
      qf[mf][kb] = q;
    }
  f32x4 acc[2][4] = {};
  float m_run[2], l_run[2];
#pragma unroll
  for (int mf = 0; mf < 2; ++mf) { m_run[mf] = -1e30f; l_run[mf] = 0.0f; }
  const int lrow = tid >> 2, lseg = tid & 3;
  short* p_w = &p_lds[wv][0];
  const int bcast = 20 * g;  // src lane 16*g + (4*g + j): holds q-row r=4g+j
  for (int kc = 0; kc < P_; kc += 64) {
    // prefetch K/V rows to registers before the barrier (overlap with prev compute)
    const short* src = qkv + (size_t)(b * P_ + kc + lrow) * TD + D_ + h * 64 + lseg * 16;
    bf16x8 kv0 = *reinterpret_cast<const bf16x8*>(src);
    bf16x8 kv1 = *reinterpret_cast<const bf16x8*>(src + 8);
    bf16x8 vv0 = *reinterpret_cast<const bf16x8*>(src + D_);
    bf16x8 vv1 = *reinterpret_cast<const bf16x8*>(src + D_ + 8);
    __syncthreads();
    *reinterpret_cast<bf16x8*>(&k_lds[lrow * 72 + lseg * 16]) = kv0;
    *reinterpret_cast<bf16x8*>(&k_lds[lrow * 72 + lseg * 16 + 8]) = kv1;
#pragma unroll
    for (int j = 0; j < 8; ++j) {
      int d0 = lseg * 16 + j, d1 = d0 + 8;
      vt_lds[d0 * 64 + (lrow ^ vswz(d0))] = vv0[j];
      vt_lds[d1 * 64 + (lrow ^ vswz(d1))] = vv1[j];
    }
    __syncthreads();
    // swapped QK^T -> S^T: lane holds S[q = mf*16+r][k = cf*16 + 4g + j]
    f32x4 st[2][4];
#pragma unroll
    for (int cf = 0; cf < 4; ++cf) {
      bf16x8 kf0 = *reinterpret_cast<const bf16x8*>(&k_lds[(cf * 16 + r) * 72 + g * 8]);
      bf16x8 kf1 = *reinterpret_cast<const bf16x8*>(&k_lds[(cf * 16 + r) * 72 + 32 + g * 8]);
#pragma unroll
      for (int mf = 0; mf < 2; ++mf) {
        f32x4 s = {};
        s = __builtin_amdgcn_mfma_f32_16x16x32_bf16(kf0, qf[mf][0], s, 0, 0, 0);
        s = __builtin_amdgcn_mfma_f32_16x16x32_bf16(kf1, qf[mf][1], s, 0, 0, 0);
        st[mf][cf] = s;
      }
    }
    // lane-local online softmax
#pragma unroll
    for (int mf = 0; mf < 2; ++mf) {
      float mx = st[mf][0][0];
#pragma unroll
      for (int cf = 0; cf < 4; ++cf)
#pragma unroll
        for (int j = 0; j < 4; ++j) mx = fmaxf(mx, st[mf][cf][j]);
      mx = fmaxf(mx, __shfl_xor(mx, 16, 64));
      mx = fmaxf(mx, __shfl_xor(mx, 32, 64));
      float mn = fmaxf(m_run[mf], mx);
      float corr = __expf(m_run[mf] - mn);
      m_run[mf] = mn;
      float p[4][4];
      float ls = 0.0f;
#pragma unroll
      for (int cf = 0; cf < 4; ++cf)
#pragma unroll
        for (int j = 0; j < 4; ++j) {
          float pv = __expf(st[mf][cf][j] - mn);
          p[cf][j] = pv;
          ls += pv;
        }
      ls += __shfl_xor(ls, 16, 64);
      ls += __shfl_xor(ls, 32, 64);
      l_run[mf] = l_run[mf] * corr + ls;
      // write P^T row (q = mf*16 + r), packed pairs, b64 per cf
      short* prow = &p_w[(mf * 16 + r) * 72];
#pragma unroll
      for (int cf = 0; cf < 4; ++cf) {
        __hip_bfloat162 lo = __float22bfloat162_rn(make_float2(p[cf][0], p[cf][1]));
        __hip_bfloat162 hi = __float22bfloat162_rn(make_float2(p[cf][2], p[cf][3]));
        union { __hip_bfloat162 h2; unsigned u; } c0, c1;
        c0.h2 = lo; c1.h2 = hi;
        *reinterpret_cast<uint2*>(&prow[cf * 16 + 4 * g]) = make_uint2(c0.u, c1.u);
      }
      // broadcast corr to the acc layout (acc row q = mf*16 + 4g + j)
      float cb0 = __shfl(corr, bcast + 0, 64);
      float cb1 = __shfl(corr, bcast + 1, 64);
      float cb2 = __shfl(corr, bcast + 2, 64);
      float cb3 = __shfl(corr, bcast + 3, 64);
#pragma unroll
      for (int cf = 0; cf < 4; ++cf) {
        acc[mf][cf][0] *= cb0; acc[mf][cf][1] *= cb1;
        acc[mf][cf][2] *= cb2; acc[mf][cf][3] *= cb3;
      }
    }
    // PV: vector V fragments from swizzled vt_lds
    bf16x8 vf[4][2];
#pragma unroll
    for (int cf = 0; cf < 4; ++cf) {
      int d = cf * 16 + r;
      int sw = vswz(d);
      vf[cf][0] = *reinterpret_cast<const bf16x8*>(&vt_lds[d * 64 + ((g * 8) ^ sw)]);
      vf[cf][1] = *reinterpret_cast<const bf16x8*>(&vt_lds[d * 64 + ((32 + g * 8) ^ sw)]);
    }
#pragma unroll
    for (int mf = 0; mf < 2; ++mf) {
      bf16x8 pf0 = *reinterpret_cast<const bf16x8*>(&p_w[(mf * 16 + r) * 72 + g * 8]);
      bf16x8 pf1 = *reinterpret_cast<const bf16x8*>(&p_w[(mf * 16 + r) * 72 + 32 + g * 8]);
#pragma unroll
      for (int cf = 0; cf < 4; ++cf) {
        acc[mf][cf] = __builtin_amdgcn_mfma_f32_16x16x32_bf16(pf0, vf[cf][0], acc[mf][cf], 0, 0, 0);
        acc[mf][cf] = __builtin_amdgcn_mfma_f32_16x16x32_bf16(pf1, vf[cf][1], acc[mf][cf], 0, 0, 0);
      }
    }
  }
#pragma unroll
  for (int mf = 0; mf < 2; ++mf) {
    float lb0 = 0.9f / __shfl(l_run[mf], bcast + 0, 64);
    float lb1 = 0.9f / __shfl(l_run[mf], bcast + 1, 64);
    float lb2 = 0.9f / __shfl(l_run[mf], bcast + 2, 64);
    float lb3 = 0.9f / __shfl(l_run[mf], bcast + 3, 64);
    float lb[4] = {lb0, lb1, lb2, lb3};
#pragma unroll
    for (int cf = 0; cf < 4; ++cf) {
      int col = h * 64 + cf * 16 + r;
#pragma unroll
      for (int j = 0; j < 4; ++j) {
        int row = qrow0 + mf * 16 + g * 4 + j;
        size_t idx = (size_t)(b * P_ + row) * D_ + col;
        x2[idx] = acc[mf][cf][j] * lb[j] + x[idx];
      }
    }
  }
}

extern "C" void kernel_launch(void* const* d_in, const int* in_sizes, int n_in,
                              void* d_out, int out_size, void* d_ws, size_t ws_size,
                              hipStream_t stream) {
  const float* x     = (const float*)d_in[0];
  const float* ln1_g = (const float*)d_in[1];
  const float* ln1_b = (const float*)d_in[2];
  const float* w_qkv = (const float*)d_in[3];
  const float* b_qkv = (const float*)d_in[4];
  const float* ln2_g = (const float*)d_in[5];
  const float* ln2_b = (const float*)d_in[6];
  const float* w1    = (const float*)d_in[7];
  const float* b1    = (const float*)d_in[8];
  const float* w2    = (const float*)d_in[9];
  const float* b2    = (const float*)d_in[10];
  float* out = (float*)d_out;
  char* ws = (char*)d_ws;

  short* wqkv_t = (short*)(ws);                 // [2304][768]
  short* w1_t   = (short*)(ws + 3538944);       // [3072][768]
  short* w2_t   = (short*)(ws + 8257536);       // [768][3072]
  short* h_bf   = (short*)(ws + 12976128);      // [8192][768]
  short* qkv_bf = (short*)(ws + 25559040);      // [8192][2304]
  short* a1_bf  = qkv_bf;                       // reused: [8192][3072]

  const int R = B_ * P_;  // 8192 rows

  { dim3 g2(768 / 32, 2304 / 32);  tcvt_kernel<<<g2, 256, 0, stream>>>(w_qkv, wqkv_t, 768, 2304); }
  { dim3 g2(768 / 32, 3072 / 32);  tcvt_kernel<<<g2, 256, 0, stream>>>(w1, w1_t, 768, 3072); }
  { dim3 g2(3072 / 32, 768 / 32);  tcvt_kernel<<<g2, 256, 0, stream>>>(w2, w2_t, 3072, 768); }

  ln_kernel<<<R, 256, 0, stream>>>(x, ln1_g, ln1_b, h_bf);

  {
    dim3 grid(R / 128, 2304 / 128);
    gemm128<0><<<grid, 256, 0, stream>>>(h_bf, wqkv_t, b_qkv, qkv_bf, nullptr, nullptr,
                                         R, 2304, 768);
  }
  {
    dim3 grid(P_ / 128, B_ * H_);
    attn_kernel<<<grid, 256, 0, stream>>>(qkv_bf, x, out);
  }
  ln_kernel<<<R, 256, 0, stream>>>(out, ln2_g, ln2_b, h_bf);
  {
    dim3 grid(R / 128, 3072 / 128);
    gemm128<1><<<grid, 256, 0, stream>>>(h_bf, w1_t, b1, a1_bf, nullptr, nullptr,
                                         R, 3072, 768);
  }
  {
    dim3 grid(R / 128, 768 / 128);
    gemm128<2><<<grid, 256, 0, stream>>>(a1_bf, w2_t, b2, nullptr, out, out,
                                         R, 768, 3072);
  }
}